// Round 5
// baseline (214.660 us; speedup 1.0000x reference)
//
#include <hip/hip_runtime.h>
#include <cstdint>
#include <cstddef>

typedef unsigned short u16;
typedef unsigned int   u32;
typedef unsigned long long u64;
typedef __attribute__((ext_vector_type(8))) short short8;   // 8 bf16 = 4 VGPR
typedef __attribute__((ext_vector_type(4))) float f32x4;

#define M_ROWS 16384
#define N_COLS 256
#define IN_F   1024
#define K_SPL  8192   // 1024 features * 8 basis
#define K_TOT  9216   // + 1024 base (silu) features
// BK=64 chunks: 144 total (128 spline chunks of 8 features, 16 base chunks of 64 feats)
#define NCHUNK 144
#define SPLITK 2
#define CPB    (NCHUNK / SPLITK)   // 72 chunks per block

// ---------- helpers ----------
__device__ __forceinline__ u32 f2bf1(float f) {          // f32 -> bf16 bits, RNE
  u32 u = __float_as_uint(f);
  u += 0x7fffu + ((u >> 16) & 1u);
  return u >> 16;
}
__device__ __forceinline__ u32 pk2(float a, float b) {
  return f2bf1(a) | (f2bf1(b) << 16);
}
__device__ __forceinline__ float silu(float v) {
  return v * __builtin_amdgcn_rcpf(1.f + __expf(-v));
}

// 8 bf16 cubic B-spline basis values for one x, packed as uint4 (16B).
// u = 2.5x + 5.5; basis_j(x) = N3(u - j); 4 nonzero wts scattered via funnel shift.
__device__ __forceinline__ uint4 basis8(float xv) {
  float u = fmaf(xv, 2.5f, 5.5f);
  int i0 = (int)u;
  float fr = u - (float)i0;
  float fr2 = fr * fr, fr3 = fr2 * fr;
  float om  = 1.f - fr;
  float om3 = om * om * om;
  float w0 = om3 * (1.f / 6.f);
  float w3 = fr3 * (1.f / 6.f);
  float w1 = fmaf(fr3, 0.5f, fmaf(fr2, -1.f, 2.f / 3.f));
  float w2 = fmaf(fr + fr2 - fr3, 0.5f, 1.f / 6.f);
  u64 W = (u64)pk2(w0, w1) | ((u64)pk2(w2, w3) << 32);
  if (!(u >= 0.f && u < 11.f)) W = 0ull;
  int s = (i0 - 3) * 16;
  u64 lo, hi;
  if (s >= 64)      { int r = s - 64; lo = 0ull; hi = (r < 64) ? (W << r) : 0ull; }
  else if (s > 0)   { lo = W << s;    hi = W >> (64 - s); }
  else if (s == 0)  { lo = W;         hi = 0ull; }
  else              { int r = -s;     lo = (r < 64) ? (W >> r) : 0ull; hi = 0ull; }
  uint4 o;
  o.x = (u32)lo; o.y = (u32)(lo >> 32); o.z = (u32)hi; o.w = (u32)(hi >> 32);
  return o;
}

// ---------- kernel 1: pack [spline_weight | base_weight] -> bf16 (256 x 9216) + zero out ----------
__global__ void pack_weights(const float* __restrict__ bw, const float* __restrict__ sw,
                             u16* __restrict__ Bp, float* __restrict__ out) {
  int o  = blockIdx.y;
  int k4 = (blockIdx.x * blockDim.x + threadIdx.x) * 4;
  const float* src = (k4 < K_SPL) ? (sw + (size_t)o * K_SPL + k4)
                                  : (bw + (size_t)o * IN_F + (k4 - K_SPL));
  float a = src[0], b = src[1], c = src[2], d = src[3];
  uint2 v; v.x = pk2(a, b); v.y = pk2(c, d);
  *(uint2*)(Bp + (size_t)o * K_TOT + k4) = v;

  // fused zero-init of out (replaces a separate memset dispatch)
  int flat = (blockIdx.y * gridDim.x + blockIdx.x) * blockDim.x + threadIdx.x;
  if (flat < (M_ROWS * N_COLS / 8)) {
    float4 z = {0.f, 0.f, 0.f, 0.f};
    ((float4*)out)[flat * 2]     = z;
    ((float4*)out)[flat * 2 + 1] = z;
  }
}

// ---------- kernel 2: fused KAN GEMM ----------
// BM=64 BN=256(=N) BK=64; 256 thr = 4 waves, EACH wave 64m x 64n (acc 4x4 of
// 16x16x32 -> 16 KB LDS read per wave-chunk, 1.5x less LDS-BW/FLOP than 32x64).
// Double-buffered As+Bs (80 KB -> 2 blocks/CU) with ONE barrier per chunk and
// distance-1 staging: the compiler's vmcnt(0)-before-barrier drains loads issued
// a full chunk earlier (hidden), not loads issued 20 instructions earlier.
// splitK=2, kid=bid&1 (R1/R4-proven: WRITE stays 2x out, no atomic storm).
// LDS 16B-chunk swizzle: chunk cc of row r at slot r*8 + (cc ^ (r&7)).
__global__ __launch_bounds__(256, 2)
void kan_gemm(const float* __restrict__ x, const u16* __restrict__ Bp,
              float* __restrict__ out) {
  __shared__ __align__(16) u16 As[2][64 * 64];    // 2 x  8 KB
  __shared__ __align__(16) u16 Bs[2][256 * 64];   // 2 x 32 KB

  const int tid  = threadIdx.x;
  const int lane = tid & 63;
  const int w    = tid >> 6;          // wave 0..3 = n-quarter

  const int bid  = blockIdx.x;        // 512
  const int kid  = bid & 1;
  const int mb   = bid >> 1;          // 0..255
  const int row0 = mb * 64;
  const int cs   = kid * CPB, c1 = cs + CPB;

  f32x4 acc[4][4];
#pragma unroll
  for (int i = 0; i < 4; ++i)
#pragma unroll
    for (int j = 0; j < 4; ++j)
      acc[i][j] = (f32x4){0.f, 0.f, 0.f, 0.f};

  const int sr = tid >> 2;            // staging row 0..63
  const int sq = tid & 3;

  // fragment read offsets (u16 index), swizzled
  const int lm = lane & 15;
  const int kg = lane >> 4;
  int a_off[2][4], b_off[2][4];
#pragma unroll
  for (int h = 0; h < 2; ++h) {
    int c = h * 4 + kg;
#pragma unroll
    for (int i = 0; i < 4; ++i) {
      int ra = i * 16 + lm;
      a_off[h][i] = ra * 64 + ((c ^ (ra & 7)) * 8);
    }
#pragma unroll
    for (int j = 0; j < 4; ++j) {
      int rb = w * 64 + j * 16 + lm;
      b_off[h][j] = rb * 64 + ((c ^ (rb & 7)) * 8);
    }
  }

  float px0, px1;       // spline prefetch: features sq, sq+4
  float4 pb0, pb1, pb2, pb3;  // base prefetch: 16 features

  auto LOADX = [&](int c) {
    if (c < 128) {
      const float* xp = x + (size_t)(row0 + sr) * IN_F + c * 8 + sq;
      px0 = xp[0];
      px1 = xp[4];
    } else {
      const float* xp = x + (size_t)(row0 + sr) * IN_F + (c - 128) * 64 + sq * 16;
      pb0 = *(const float4*)xp;
      pb1 = *(const float4*)(xp + 4);
      pb2 = *(const float4*)(xp + 8);
      pb3 = *(const float4*)(xp + 12);
    }
  };

  auto BUILD = [&](int c, u16* A) {
    if (c < 128) {
      *(uint4*)(A + sr * 64 + ((sq ^ (sr & 7)) * 8))       = basis8(px0);
      *(uint4*)(A + sr * 64 + (((sq + 4) ^ (sr & 7)) * 8)) = basis8(px1);
    } else {
      uint4 q0, q1;
      q0.x = pk2(silu(pb0.x), silu(pb0.y));
      q0.y = pk2(silu(pb0.z), silu(pb0.w));
      q0.z = pk2(silu(pb1.x), silu(pb1.y));
      q0.w = pk2(silu(pb1.z), silu(pb1.w));
      q1.x = pk2(silu(pb2.x), silu(pb2.y));
      q1.y = pk2(silu(pb2.z), silu(pb2.w));
      q1.z = pk2(silu(pb3.x), silu(pb3.y));
      q1.w = pk2(silu(pb3.z), silu(pb3.w));
      int cc0 = sq * 2, cc1 = sq * 2 + 1;
      *(uint4*)(A + sr * 64 + ((cc0 ^ (sr & 7)) * 8)) = q0;
      *(uint4*)(A + sr * 64 + ((cc1 ^ (sr & 7)) * 8)) = q1;
    }
  };

  auto STAGEB = [&](int c, u16* B) {
#pragma unroll
    for (int it = 0; it < 8; ++it) {
      int s = tid + it * 256;
      int r_ = s >> 3, cc = (s & 7) ^ (r_ & 7);
      const u16* gp = Bp + (size_t)r_ * K_TOT + c * 64 + cc * 8;
      __builtin_amdgcn_global_load_lds((const __attribute__((address_space(1))) void*)gp,
                                       (__attribute__((address_space(3))) void*)(B + s * 8),
                                       16, 0, 0);
    }
  };

  // prologue: stage chunk cs into buffer 0, prefetch x for cs+1
  LOADX(cs);
  BUILD(cs, As[0]);
  STAGEB(cs, Bs[0]);
  LOADX(cs + 1);
  __syncthreads();

  int b = 0;
  for (int c = cs; c < c1; ++c) {
    // stage c+1 into the other buffer (drained only at NEXT iteration's barrier)
    if (c + 1 < c1) {
      STAGEB(c + 1, Bs[b ^ 1]);
      BUILD(c + 1, As[b ^ 1]);        // consumes x regs loaded last iteration
      if (c + 2 < c1) LOADX(c + 2);   // refill x regs
    }
    // compute on buffer b
    const u16* Ab = As[b];
    const u16* Bb = Bs[b];
#pragma unroll
    for (int h = 0; h < 2; ++h) {
      short8 af[4], bf[4];
#pragma unroll
      for (int i = 0; i < 4; ++i) af[i] = *(const short8*)(Ab + a_off[h][i]);
#pragma unroll
      for (int j = 0; j < 4; ++j) bf[j] = *(const short8*)(Bb + b_off[h][j]);
#pragma unroll
      for (int i = 0; i < 4; ++i)
#pragma unroll
        for (int j = 0; j < 4; ++j)
          acc[i][j] = __builtin_amdgcn_mfma_f32_16x16x32_bf16(af[i], bf[j], acc[i][j], 0, 0, 0);
    }
    __syncthreads();   // releases buffer b for restaging; publishes buffer b^1
    b ^= 1;
  }

  // ---- epilogue: C/D layout col=lane&15, row=(lane>>4)*4+reg; splitK=2 -> atomic add ----
  const int lc = lane & 15;
  const int lr = (lane >> 4) * 4;
#pragma unroll
  for (int i = 0; i < 4; ++i) {
#pragma unroll
    for (int j = 0; j < 4; ++j) {
      int gr = row0 + i * 16 + lr;
      int gc = w * 64 + j * 16 + lc;
      float* po = out + (size_t)gr * N_COLS + gc;
#pragma unroll
      for (int r = 0; r < 4; ++r)
        unsafeAtomicAdd(po + (size_t)r * N_COLS, acc[i][j][r]);
    }
  }
}

extern "C" void kernel_launch(void* const* d_in, const int* in_sizes, int n_in,
                              void* d_out, int out_size, void* d_ws, size_t ws_size,
                              hipStream_t stream) {
  const float* x  = (const float*)d_in[0];   // 16384 x 1024
  const float* bw = (const float*)d_in[1];   // 256 x 1024
  const float* sw = (const float*)d_in[2];   // 256 x 8192
  float* out = (float*)d_out;                // 16384 x 256 f32
  u16* Bp = (u16*)d_ws;                      // 256 x 9216 bf16 = 4.5 MB

  dim3 pgrid(K_TOT / 4 / 256, N_COLS);       // (9, 256); also zeroes `out`
  pack_weights<<<pgrid, 256, 0, stream>>>(bw, sw, Bp, out);

  kan_gemm<<<M_ROWS / 64 * SPLITK, 256, 0, stream>>>(x, Bp, out);
}